// Round 4
// baseline (142.269 us; speedup 1.0000x reference)
//
#include <hip/hip_runtime.h>
#include <hip/hip_bf16.h>
#include <stdint.h>
#include <math.h>

// Problem constants
#define VOCAB 1000000
#define D 128
#define NROWS 16384
#define NSAMP 8192
#define SSPLIT 8                       // flash: S split across 8 block groups
#define K1F 28.853900817779268f        // (1/TEMP)*log2(e) = 20*log2(e)
#define LOG2EF 1.4426950408889634f
#define FIN_BLOCKS 4096

// ws layout (bytes)
#define EF_OFF 0u                      // S*D bf16 = 2 MB, fragment-major (normalized)
#define PS_OFF 2097152u                // psum fp32 [SSPLIT][N] = 512 KB
#define FIN_OFF 2621440u               // fin fp32 [FIN_BLOCKS][2] = 32 KB
#define CNT_OFF 2654208u               // atomic counter (zeroed per launch)

typedef __attribute__((ext_vector_type(8))) __bf16 bf16x8;
typedef __attribute__((ext_vector_type(16))) float f32x16;

#if __has_builtin(__builtin_amdgcn_exp2f)
#define EXP2(x) __builtin_amdgcn_exp2f(x)
#else
#define EXP2(x) exp2f(x)
#endif

__device__ __forceinline__ void gl_lds16(const void* g, void* l) {
  __builtin_amdgcn_global_load_lds(
      (const __attribute__((address_space(1))) unsigned int*)g,
      (__attribute__((address_space(3))) unsigned int*)l, 16, 0, 0);
}

__device__ __forceinline__ float wave_sum(float v) {
#pragma unroll
  for (int o = 1; o < 64; o <<= 1) v += __shfl_xor(v, o);
  return v;
}

// E prep: gather projection[neg_ids], L2-normalize, store bf16 fragment-major.
__global__ void prep_e_kernel(const int* __restrict__ nid,
                              const float* __restrict__ proj,
                              __bf16* __restrict__ ef) {
  const int wave = threadIdx.x >> 6, lane = threadIdx.x & 63;
  const int s = blockIdx.x * 4 + wave;
  const int id = nid[s];
  const float2 er = *reinterpret_cast<const float2*>(proj + (size_t)id * D + lane * 2);
  const float rn = 1.f / (sqrtf(wave_sum(er.x * er.x + er.y * er.y)) + 1e-12f);
  const int d = lane * 2;
  const int kk = d >> 4, sub = (d & 15) >> 3, j = d & 7;
  const int tile = s >> 5, lt = (sub << 5) | (s & 31);
  __bf16* dst = ef + ((((size_t)tile * 8 + kk) * 64 + lt) * 8 + j);
  dst[0] = (__bf16)(er.x * rn);
  dst[1] = (__bf16)(er.y * rn);
}

// Flash kernel: block = 256 rows of X (8 waves x 32 cols each), loops over a
// 1024-s slice of E in 16 64-s supertiles (double-buffered LDS via
// global_load_lds). B-fragments are built in-kernel from raw fp32 x (bf16
// cast, UNNORMALIZED); the per-row scale K1F/||x|| folds into the exp2
// argument (C-col == lane&31 == row). psum[ss][n] += sum_s exp2(logit*log2e).
__global__ __launch_bounds__(512, 4) void flash_kernel(
    const float* __restrict__ x, const __bf16* __restrict__ ef,
    float* __restrict__ psum) {
  __shared__ __align__(16) char lds[2][16384];
  const int tid = threadIdx.x, wave = tid >> 6, lane = tid & 63;
  const int nb = blockIdx.x & 63, ss = blockIdx.x >> 6;  // bid%8==nb%8 -> XCD-local x reuse
  const int sub = lane >> 5;
  const int row = nb * 256 + wave * 32 + (lane & 31);

  // stage supertile 0 early (loads in flight under the X-prep VALU below)
  const char* esrc = reinterpret_cast<const char*>(ef) + (size_t)ss * 262144;
  {
    const char* g = esrc + wave * 1024 + lane * 16;
    char* l = &lds[0][0] + wave * 1024;
    gl_lds16(g, l);
    gl_lds16(g + 8192, l + 8192);
  }

  // Build B fragments: lane supplies row (lane&31), dims d = kk*16 + sub*8 + j.
  const float* xrow = x + (size_t)row * D + sub * 8;
  float ssq = 0.f;
  bf16x8 bq[8];
#pragma unroll
  for (int kk = 0; kk < 8; ++kk) {
    const float4 a0 = *reinterpret_cast<const float4*>(xrow + kk * 16);
    const float4 a1 = *reinterpret_cast<const float4*>(xrow + kk * 16 + 4);
    ssq += a0.x * a0.x + a0.y * a0.y + a0.z * a0.z + a0.w * a0.w
         + a1.x * a1.x + a1.y * a1.y + a1.z * a1.z + a1.w * a1.w;
    bf16x8 b;
    b[0] = (__bf16)a0.x; b[1] = (__bf16)a0.y; b[2] = (__bf16)a0.z; b[3] = (__bf16)a0.w;
    b[4] = (__bf16)a1.x; b[5] = (__bf16)a1.y; b[6] = (__bf16)a1.z; b[7] = (__bf16)a1.w;
    bq[kk] = b;
  }
  ssq += __shfl_xor(ssq, 32);                    // partner lane holds other half
  const float sn = K1F / (sqrtf(ssq) + 1e-12f);  // row scale, folded into exp arg

  float acc = 0.f;
  __syncthreads();

  for (int st = 0; st < 16; ++st) {
    if (st < 15) {  // prefetch next supertile into the other buffer
      const char* g = esrc + (size_t)(st + 1) * 16384 + wave * 1024 + lane * 16;
      char* l = &lds[(st + 1) & 1][0] + wave * 1024;
      gl_lds16(g, l);
      gl_lds16(g + 8192, l + 8192);
    }
    const char* cb = &lds[st & 1][0];
#pragma unroll
    for (int tt = 0; tt < 2; ++tt) {
      f32x16 c;
#pragma unroll
      for (int r = 0; r < 16; ++r) c[r] = 0.f;
      const char* ab = cb + tt * 8192 + lane * 16;
#pragma unroll
      for (int kk = 0; kk < 8; ++kk) {
        bf16x8 a = *reinterpret_cast<const bf16x8*>(ab + kk * 1024);
        c = __builtin_amdgcn_mfma_f32_32x32x16_bf16(a, bq[kk], c, 0, 0, 0);
      }
      float e[16];
#pragma unroll
      for (int r = 0; r < 16; ++r) e[r] = EXP2(c[r] * sn);
#pragma unroll
      for (int s2 = 8; s2; s2 >>= 1)
#pragma unroll
        for (int r = 0; r < s2; ++r) e[r] += e[r + s2];
      acc += e[0];
    }
    __syncthreads();
  }

  // lanes l and l+32 hold different s-rows of the same column n: combine.
  acc += __shfl_xor(acc, 32);
  if (lane < 32) {
    const int nbase = nb * 256 + wave * 32;
    psum[(size_t)ss * NROWS + nbase + lane] = acc;
  }
}

// Fused finish: per-row exact fp32 pos logit (tgt gather) + CE + weighted
// partials; last-arriving block does the deterministic final reduction.
__global__ void finish_kernel(const float* __restrict__ x,
                              const int* __restrict__ tgt,
                              const float* __restrict__ wts,
                              const float* __restrict__ proj,
                              const float* __restrict__ psum,
                              float* __restrict__ fin,
                              unsigned int* __restrict__ cnt,
                              float* __restrict__ out) {
  const int wave = threadIdx.x >> 6, lane = threadIdx.x & 63;
  const int n = blockIdx.x * 4 + wave;
  const float2 xr = *reinterpret_cast<const float2*>(x + (size_t)n * D + lane * 2);
  const float rnx = 1.f / (sqrtf(wave_sum(xr.x * xr.x + xr.y * xr.y)) + 1e-12f);
  const int t = tgt[n];
  const int tg = t < 0 ? 0 : (t > VOCAB - 1 ? VOCAB - 1 : t);
  const float2 pr = *reinterpret_cast<const float2*>(proj + (size_t)tg * D + lane * 2);
  const float rnp = 1.f / (sqrtf(wave_sum(pr.x * pr.x + pr.y * pr.y)) + 1e-12f);
  const float p = wave_sum(xr.x * pr.x + xr.y * pr.y) * rnx * rnp * 20.0f;
  const float v = (lane < SSPLIT) ? psum[(size_t)lane * NROWS + n] : 0.f;
  const float tot = wave_sum(v) + EXP2(p * LOG2EF);
  const float ce = logf(tot) - p;                 // logZ - pos_logit
  const float w = wts[n] * (t != -100 ? 1.f : 0.f);

  __shared__ float sa[4], sb[4];
  if (lane == 0) { sa[wave] = ce * w; sb[wave] = w; }
  __syncthreads();
  if (threadIdx.x == 0) {
    __hip_atomic_store(&fin[blockIdx.x * 2], sa[0] + sa[1] + sa[2] + sa[3],
                       __ATOMIC_RELAXED, __HIP_MEMORY_SCOPE_AGENT);
    __hip_atomic_store(&fin[blockIdx.x * 2 + 1], sb[0] + sb[1] + sb[2] + sb[3],
                       __ATOMIC_RELAXED, __HIP_MEMORY_SCOPE_AGENT);
  }
  __shared__ int is_last;
  if (threadIdx.x == 0) {
    const unsigned int old = __hip_atomic_fetch_add(cnt, 1u, __ATOMIC_ACQ_REL,
                                                    __HIP_MEMORY_SCOPE_AGENT);
    is_last = (old == FIN_BLOCKS - 1);
  }
  __syncthreads();
  if (is_last) {  // block-uniform
    float A = 0.f, B = 0.f;
    for (int i = threadIdx.x; i < FIN_BLOCKS; i += 256) {  // fixed order
      A += __hip_atomic_load(&fin[i * 2], __ATOMIC_RELAXED, __HIP_MEMORY_SCOPE_AGENT);
      B += __hip_atomic_load(&fin[i * 2 + 1], __ATOMIC_RELAXED, __HIP_MEMORY_SCOPE_AGENT);
    }
    A = wave_sum(A);
    B = wave_sum(B);
    __shared__ float ra[4], rb[4];
    if (lane == 0) { ra[wave] = A; rb[wave] = B; }
    __syncthreads();
    if (threadIdx.x == 0)
      out[0] = (ra[0] + ra[1] + ra[2] + ra[3]) /
               fmaxf(rb[0] + rb[1] + rb[2] + rb[3], 1e-12f);
  }
}

extern "C" void kernel_launch(void* const* d_in, const int* in_sizes, int n_in,
                              void* d_out, int out_size, void* d_ws, size_t ws_size,
                              hipStream_t stream) {
  const float* x    = (const float*)d_in[0];
  const int*   tgt  = (const int*)d_in[1];
  const int*   nid  = (const int*)d_in[2];
  const float* wts  = (const float*)d_in[3];
  const float* proj = (const float*)d_in[4];
  float* out = (float*)d_out;
  char* ws = (char*)d_ws;
  __bf16* ef  = (__bf16*)(ws + EF_OFF);
  float* psum = (float*)(ws + PS_OFF);
  float* fin  = (float*)(ws + FIN_OFF);
  unsigned int* cnt = (unsigned int*)(ws + CNT_OFF);

  hipMemsetAsync(cnt, 0, 4, stream);  // counter must start at 0 every launch
  hipLaunchKernelGGL(prep_e_kernel, dim3(NSAMP / 4), dim3(256), 0, stream,
                     nid, proj, ef);
  hipLaunchKernelGGL(flash_kernel, dim3(64 * SSPLIT), dim3(512), 0, stream,
                     x, ef, psum);
  hipLaunchKernelGGL(finish_kernel, dim3(FIN_BLOCKS), dim3(256), 0, stream,
                     x, tgt, wts, proj, psum, fin, cnt, out);
}

// Round 5
// 63.222 us; speedup vs baseline: 2.2503x; 2.2503x over previous
//
#include <hip/hip_runtime.h>
#include <hip/hip_bf16.h>
#include <stdint.h>
#include <math.h>

// Problem constants
#define VOCAB 1000000
#define D 128
#define NROWS 16384
#define NSAMP 8192
#define SSPLIT 8                       // flash: S split across 8 block groups
#define K1F 28.853900817779268f        // (1/TEMP)*log2(e) = 20*log2(e)
#define LOG2EF 1.4426950408889634f
#define FIN_BLOCKS 512

// ws layout (bytes)
#define EF_OFF 0u                      // S*D bf16 = 2 MB, fragment-major (normalized)
#define PS_OFF 2097152u                // psum fp32 [SSPLIT][N] = 512 KB
#define FIN_OFF 2621440u               // fin fp32 [FIN_BLOCKS][2] = 4 KB
#define CNT_OFF 2629632u               // atomic counter (zeroed by prep_e each launch)

typedef __attribute__((ext_vector_type(8))) __bf16 bf16x8;
typedef __attribute__((ext_vector_type(16))) float f32x16;

#if __has_builtin(__builtin_amdgcn_exp2f)
#define EXP2(x) __builtin_amdgcn_exp2f(x)
#else
#define EXP2(x) exp2f(x)
#endif

__device__ __forceinline__ void gl_lds16(const void* g, void* l) {
  __builtin_amdgcn_global_load_lds(
      (const __attribute__((address_space(1))) unsigned int*)g,
      (__attribute__((address_space(3))) unsigned int*)l, 16, 0, 0);
}

__device__ __forceinline__ float wave_sum(float v) {
#pragma unroll
  for (int o = 1; o < 64; o <<= 1) v += __shfl_xor(v, o);
  return v;
}

// E prep: gather projection[neg_ids], L2-normalize, store bf16 fragment-major.
// Also zeroes the finish counter (stream-ordered before finish_kernel).
__global__ void prep_e_kernel(const int* __restrict__ nid,
                              const float* __restrict__ proj,
                              __bf16* __restrict__ ef,
                              unsigned int* __restrict__ cnt) {
  if (blockIdx.x == 0 && threadIdx.x == 0) *cnt = 0u;
  const int wave = threadIdx.x >> 6, lane = threadIdx.x & 63;
  const int s = blockIdx.x * 4 + wave;
  const int id = nid[s];
  const float2 er = *reinterpret_cast<const float2*>(proj + (size_t)id * D + lane * 2);
  const float rn = 1.f / (sqrtf(wave_sum(er.x * er.x + er.y * er.y)) + 1e-12f);
  const int d = lane * 2;
  const int kk = d >> 4, sub = (d & 15) >> 3, j = d & 7;
  const int tile = s >> 5, lt = (sub << 5) | (s & 31);
  __bf16* dst = ef + ((((size_t)tile * 8 + kk) * 64 + lt) * 8 + j);
  dst[0] = (__bf16)(er.x * rn);
  dst[1] = (__bf16)(er.y * rn);
}

// Flash kernel: block = 256 rows of X (8 waves x 32 cols each), loops over a
// 1024-s slice of E in 16 64-s supertiles (double-buffered LDS via
// global_load_lds). B-fragments are built in-kernel from raw fp32 x (bf16
// cast, UNNORMALIZED); the per-row scale K1F/||x|| folds into the exp2
// argument (C-col == lane&31 == row). psum[ss][n] = sum_s exp2(logit*log2e).
__global__ __launch_bounds__(512, 4) void flash_kernel(
    const float* __restrict__ x, const __bf16* __restrict__ ef,
    float* __restrict__ psum) {
  __shared__ __align__(16) char lds[2][16384];
  const int tid = threadIdx.x, wave = tid >> 6, lane = tid & 63;
  const int nb = blockIdx.x & 63, ss = blockIdx.x >> 6;  // bid%8==nb%8 -> XCD-local x reuse
  const int sub = lane >> 5;
  const int row = nb * 256 + wave * 32 + (lane & 31);

  // stage supertile 0 early (loads in flight under the X-prep VALU below)
  const char* esrc = reinterpret_cast<const char*>(ef) + (size_t)ss * 262144;
  {
    const char* g = esrc + wave * 1024 + lane * 16;
    char* l = &lds[0][0] + wave * 1024;
    gl_lds16(g, l);
    gl_lds16(g + 8192, l + 8192);
  }

  // Build B fragments: lane supplies row (lane&31), dims d = kk*16 + sub*8 + j.
  const float* xrow = x + (size_t)row * D + sub * 8;
  float ssq = 0.f;
  bf16x8 bq[8];
#pragma unroll
  for (int kk = 0; kk < 8; ++kk) {
    const float4 a0 = *reinterpret_cast<const float4*>(xrow + kk * 16);
    const float4 a1 = *reinterpret_cast<const float4*>(xrow + kk * 16 + 4);
    ssq += a0.x * a0.x + a0.y * a0.y + a0.z * a0.z + a0.w * a0.w
         + a1.x * a1.x + a1.y * a1.y + a1.z * a1.z + a1.w * a1.w;
    bf16x8 b;
    b[0] = (__bf16)a0.x; b[1] = (__bf16)a0.y; b[2] = (__bf16)a0.z; b[3] = (__bf16)a0.w;
    b[4] = (__bf16)a1.x; b[5] = (__bf16)a1.y; b[6] = (__bf16)a1.z; b[7] = (__bf16)a1.w;
    bq[kk] = b;
  }
  ssq += __shfl_xor(ssq, 32);                    // partner lane holds other half
  const float sn = K1F / (sqrtf(ssq) + 1e-12f);  // row scale, folded into exp arg

  float acc = 0.f;
  __syncthreads();

  for (int st = 0; st < 16; ++st) {
    if (st < 15) {  // prefetch next supertile into the other buffer
      const char* g = esrc + (size_t)(st + 1) * 16384 + wave * 1024 + lane * 16;
      char* l = &lds[(st + 1) & 1][0] + wave * 1024;
      gl_lds16(g, l);
      gl_lds16(g + 8192, l + 8192);
    }
    const char* cb = &lds[st & 1][0];
#pragma unroll
    for (int tt = 0; tt < 2; ++tt) {
      f32x16 c;
#pragma unroll
      for (int r = 0; r < 16; ++r) c[r] = 0.f;
      const char* ab = cb + tt * 8192 + lane * 16;
#pragma unroll
      for (int kk = 0; kk < 8; ++kk) {
        bf16x8 a = *reinterpret_cast<const bf16x8*>(ab + kk * 1024);
        c = __builtin_amdgcn_mfma_f32_32x32x16_bf16(a, bq[kk], c, 0, 0, 0);
      }
      float e[16];
#pragma unroll
      for (int r = 0; r < 16; ++r) e[r] = EXP2(c[r] * sn);
#pragma unroll
      for (int s2 = 8; s2; s2 >>= 1)
#pragma unroll
        for (int r = 0; r < s2; ++r) e[r] += e[r + s2];
      acc += e[0];
    }
    __syncthreads();
  }

  // lanes l and l+32 hold different s-rows of the same column n: combine.
  acc += __shfl_xor(acc, 32);
  if (lane < 32) {
    const int nbase = nb * 256 + wave * 32;
    psum[(size_t)ss * NROWS + nbase + lane] = acc;
  }
}

// Fused finish: each wave handles 8 rows. psum splits reduced with 3
// xor-shuffles (lane = split*8 + row layout); per-row exact fp32 pos logit
// (tgt gather) + CE + weighted partials; last block does the final reduction.
__global__ __launch_bounds__(256) void finish_kernel(
    const float* __restrict__ x,
    const int* __restrict__ tgt,
    const float* __restrict__ wts,
    const float* __restrict__ proj,
    const float* __restrict__ psum,
    float* __restrict__ fin,
    unsigned int* __restrict__ cnt,
    float* __restrict__ out) {
  const int wave = threadIdx.x >> 6, lane = threadIdx.x & 63;
  const int n0 = (blockIdx.x * 4 + wave) * 8;

  // psum totals: lane = s*8 + r reads split s of row n0+r; reduce over s.
  float tot = psum[(size_t)(lane >> 3) * NROWS + n0 + (lane & 7)];
  tot += __shfl_xor(tot, 8);
  tot += __shfl_xor(tot, 16);
  tot += __shfl_xor(tot, 32);          // lane r (r<8) holds row n0+r total

  // per-row target/weight, staged in lanes 0..7
  const int tv = (lane < 8) ? tgt[n0 + lane] : 0;
  const float wv = (lane < 8) ? wts[n0 + lane] : 0.f;

  float a_acc = 0.f, b_acc = 0.f;
#pragma unroll
  for (int i = 0; i < 8; ++i) {
    const int n = n0 + i;
    const float2 xr = *reinterpret_cast<const float2*>(x + (size_t)n * D + lane * 2);
    const float rnx = 1.f / (sqrtf(wave_sum(xr.x * xr.x + xr.y * xr.y)) + 1e-12f);
    const int ti = __shfl(tv, i);
    const int tg = ti < 0 ? 0 : (ti > VOCAB - 1 ? VOCAB - 1 : ti);
    const float2 pr = *reinterpret_cast<const float2*>(proj + (size_t)tg * D + lane * 2);
    const float rnp = 1.f / (sqrtf(wave_sum(pr.x * pr.x + pr.y * pr.y)) + 1e-12f);
    const float p = wave_sum(xr.x * pr.x + xr.y * pr.y) * rnx * rnp * 20.0f;
    const float tr = __shfl(tot, i);
    const float Z = tr + EXP2(p * LOG2EF);
    const float ce = logf(Z) - p;      // logZ - pos_logit
    const float w = __shfl(wv, i) * (ti != -100 ? 1.f : 0.f);
    a_acc += ce * w;
    b_acc += w;
  }

  __shared__ float sa[4], sb[4];
  if (lane == 0) { sa[wave] = a_acc; sb[wave] = b_acc; }
  __syncthreads();
  if (threadIdx.x == 0) {
    __hip_atomic_store(&fin[blockIdx.x * 2], sa[0] + sa[1] + sa[2] + sa[3],
                       __ATOMIC_RELAXED, __HIP_MEMORY_SCOPE_AGENT);
    __hip_atomic_store(&fin[blockIdx.x * 2 + 1], sb[0] + sb[1] + sb[2] + sb[3],
                       __ATOMIC_RELAXED, __HIP_MEMORY_SCOPE_AGENT);
  }
  __shared__ int is_last;
  if (threadIdx.x == 0) {
    const unsigned int old = __hip_atomic_fetch_add(cnt, 1u, __ATOMIC_ACQ_REL,
                                                    __HIP_MEMORY_SCOPE_AGENT);
    is_last = (old == FIN_BLOCKS - 1);
  }
  __syncthreads();
  if (is_last) {  // block-uniform
    float A = 0.f, B = 0.f;
    for (int i = threadIdx.x; i < FIN_BLOCKS; i += 256) {  // fixed order
      A += __hip_atomic_load(&fin[i * 2], __ATOMIC_RELAXED, __HIP_MEMORY_SCOPE_AGENT);
      B += __hip_atomic_load(&fin[i * 2 + 1], __ATOMIC_RELAXED, __HIP_MEMORY_SCOPE_AGENT);
    }
    A = wave_sum(A);
    B = wave_sum(B);
    __shared__ float ra[4], rb[4];
    if (lane == 0) { ra[wave] = A; rb[wave] = B; }
    __syncthreads();
    if (threadIdx.x == 0)
      out[0] = (ra[0] + ra[1] + ra[2] + ra[3]) /
               fmaxf(rb[0] + rb[1] + rb[2] + rb[3], 1e-12f);
  }
}

extern "C" void kernel_launch(void* const* d_in, const int* in_sizes, int n_in,
                              void* d_out, int out_size, void* d_ws, size_t ws_size,
                              hipStream_t stream) {
  const float* x    = (const float*)d_in[0];
  const int*   tgt  = (const int*)d_in[1];
  const int*   nid  = (const int*)d_in[2];
  const float* wts  = (const float*)d_in[3];
  const float* proj = (const float*)d_in[4];
  float* out = (float*)d_out;
  char* ws = (char*)d_ws;
  __bf16* ef  = (__bf16*)(ws + EF_OFF);
  float* psum = (float*)(ws + PS_OFF);
  float* fin  = (float*)(ws + FIN_OFF);
  unsigned int* cnt = (unsigned int*)(ws + CNT_OFF);

  hipLaunchKernelGGL(prep_e_kernel, dim3(NSAMP / 4), dim3(256), 0, stream,
                     nid, proj, ef, cnt);
  hipLaunchKernelGGL(flash_kernel, dim3(64 * SSPLIT), dim3(512), 0, stream,
                     x, ef, psum);
  hipLaunchKernelGGL(finish_kernel, dim3(FIN_BLOCKS), dim3(256), 0, stream,
                     x, tgt, wts, proj, psum, fin, cnt, out);
}

// Round 6
// 52.353 us; speedup vs baseline: 2.7175x; 1.2076x over previous
//
#include <hip/hip_runtime.h>
#include <hip/hip_bf16.h>
#include <stdint.h>
#include <math.h>

// Problem constants
#define VOCAB 1000000
#define D 128
#define NROWS 16384
#define NSAMP 8192
#define SSPLIT 8                       // flash: S split across 8 block groups
#define K1F 28.853900817779268f        // (1/TEMP)*log2(e) = 20*log2(e)
#define LOG2EF 1.4426950408889634f

// ws layout (bytes)
#define XF_OFF 0u                      // N*D bf16 = 4 MB, fragment-major, pre-scaled by K1F
#define EF_OFF 4194304u                // S*D bf16 = 2 MB, fragment-major
#define PL_OFF 6291456u                // pos_logit fp32 [N]
#define PS_OFF 6356992u                // psum fp32 [SSPLIT][N] = 512 KB
#define FP_OFF 6881280u                // finish partials [64][2]

typedef __attribute__((ext_vector_type(8))) __bf16 bf16x8;
typedef __attribute__((ext_vector_type(16))) float f32x16;

#if __has_builtin(__builtin_amdgcn_exp2f)
#define EXP2(x) __builtin_amdgcn_exp2f(x)
#else
#define EXP2(x) exp2f(x)
#endif

__device__ __forceinline__ void gl_lds16(const void* g, void* l) {
  __builtin_amdgcn_global_load_lds(
      (const __attribute__((address_space(1))) unsigned int*)g,
      (__attribute__((address_space(3))) unsigned int*)l, 16, 0, 0);
}

__device__ __forceinline__ float wave_sum(float v) {
#pragma unroll
  for (int o = 1; o < 64; o <<= 1) v += __shfl_xor(v, o);
  return v;
}

// exp2 each of 16 fp32 and tree-sum (short dependent chains).
__device__ __forceinline__ float expsum16(const f32x16& c) {
  float e[16];
#pragma unroll
  for (int r = 0; r < 16; ++r) e[r] = EXP2(c[r]);
#pragma unroll
  for (int s = 8; s; s >>= 1)
#pragma unroll
    for (int r = 0; r < s; ++r) e[r] += e[r + s];
  return e[0];
}

// Merged prep: blocks [0,4096) handle X rows (normalize, pre-scale by K1F,
// fragment-major bf16 store, fp32 pos logit); blocks [4096,6144) handle E rows.
__global__ void prep_kernel(const float* __restrict__ x,
                            const int* __restrict__ tgt,
                            const int* __restrict__ nid,
                            const float* __restrict__ proj,
                            __bf16* __restrict__ xf,
                            __bf16* __restrict__ ef,
                            float* __restrict__ pl) {
  const int wave = threadIdx.x >> 6, lane = threadIdx.x & 63;
  const int d = lane * 2;
  const int kk = d >> 4, sub = (d & 15) >> 3, j = d & 7;
  if (blockIdx.x < 4096) {
    const int n = blockIdx.x * 4 + wave;
    const float2 xr = *reinterpret_cast<const float2*>(x + (size_t)n * D + lane * 2);
    const float rnx = 1.f / (sqrtf(wave_sum(xr.x * xr.x + xr.y * xr.y)) + 1e-12f);
    const int t = tgt[n];
    const int tg = t < 0 ? 0 : (t > VOCAB - 1 ? VOCAB - 1 : t);
    const float2 pr = *reinterpret_cast<const float2*>(proj + (size_t)tg * D + lane * 2);
    const float rnp = 1.f / (sqrtf(wave_sum(pr.x * pr.x + pr.y * pr.y)) + 1e-12f);
    const float dt = wave_sum(xr.x * pr.x + xr.y * pr.y);
    if (lane == 0) pl[n] = dt * rnx * rnp * 20.0f;  // /TEMP, exact fp32
    const int tile = n >> 5, lt = (sub << 5) | (n & 31);
    __bf16* dst = xf + ((((size_t)tile * 8 + kk) * 64 + lt) * 8 + j);
    const float s = rnx * K1F;  // fold logit scale (in log2 base) into X
    dst[0] = (__bf16)(xr.x * s);
    dst[1] = (__bf16)(xr.y * s);
  } else {
    const int s = (blockIdx.x - 4096) * 4 + wave;
    const int id = nid[s];
    const float2 er = *reinterpret_cast<const float2*>(proj + (size_t)id * D + lane * 2);
    const float rn = 1.f / (sqrtf(wave_sum(er.x * er.x + er.y * er.y)) + 1e-12f);
    const int tile = s >> 5, lt = (sub << 5) | (s & 31);
    __bf16* dst = ef + ((((size_t)tile * 8 + kk) * 64 + lt) * 8 + j);
    dst[0] = (__bf16)(er.x * rn);
    dst[1] = (__bf16)(er.y * rn);
  }
}

// Flash kernel, F=2: block = 4 waves x 2 n-frags (256 X-cols), loops over a
// 1024-s slice of E in 16 64-s supertiles (double-buffered LDS via
// global_load_lds). Each 1 KB A-frag ds_read now feeds TWO MFMAs -> LDS read
// traffic halves vs F=1. ~140 VGPR under the (256,3) cap -> 3 blocks/CU.
__global__ __launch_bounds__(256, 3) void flash_kernel(
    const __bf16* __restrict__ xf, const __bf16* __restrict__ ef,
    float* __restrict__ psum) {
  __shared__ __align__(16) char lds[2][16384];
  const int tid = threadIdx.x, wave = tid >> 6, lane = tid & 63;
  const int nb = blockIdx.x & 63, ss = blockIdx.x >> 6;

  // B fragments (X): 2 n-frags (64 rows) x 8 k-steps, from frag-major xf.
  bf16x8 bq[2][8];
#pragma unroll
  for (int nf = 0; nf < 2; ++nf) {
    const __bf16* p = xf + ((size_t)(nb * 8 + wave * 2 + nf) * 4096) + lane * 8;
#pragma unroll
    for (int kk = 0; kk < 8; ++kk)
      bq[nf][kk] = *reinterpret_cast<const bf16x8*>(p + kk * 512);
  }

  const char* esrc = reinterpret_cast<const char*>(ef) + (size_t)ss * 262144;
  float acc0 = 0.f, acc1 = 0.f;

  {  // stage supertile 0 (4 waves x 4 chunks of 1 KB each)
    const char* g = esrc + wave * 1024 + lane * 16;
    char* l = &lds[0][0] + wave * 1024;
#pragma unroll
    for (int i = 0; i < 4; ++i) gl_lds16(g + i * 4096, l + i * 4096);
  }
  __syncthreads();

  for (int st = 0; st < 16; ++st) {
    if (st < 15) {  // prefetch next supertile into the other buffer
      const char* g = esrc + (size_t)(st + 1) * 16384 + wave * 1024 + lane * 16;
      char* l = &lds[(st + 1) & 1][0] + wave * 1024;
#pragma unroll
      for (int i = 0; i < 4; ++i) gl_lds16(g + i * 4096, l + i * 4096);
    }
    const char* cb = &lds[st & 1][0];
#pragma unroll
    for (int tt = 0; tt < 2; ++tt) {
      f32x16 c0, c1;
#pragma unroll
      for (int r = 0; r < 16; ++r) { c0[r] = 0.f; c1[r] = 0.f; }
      const char* ab = cb + tt * 8192 + lane * 16;
#pragma unroll
      for (int kk = 0; kk < 8; ++kk) {
        bf16x8 a = *reinterpret_cast<const bf16x8*>(ab + kk * 1024);
        c0 = __builtin_amdgcn_mfma_f32_32x32x16_bf16(a, bq[0][kk], c0, 0, 0, 0);
        c1 = __builtin_amdgcn_mfma_f32_32x32x16_bf16(a, bq[1][kk], c1, 0, 0, 0);
      }
      acc0 += expsum16(c0);
      acc1 += expsum16(c1);
    }
    __syncthreads();
  }

  // lanes l and l+32 hold different s-rows of the same column n: combine.
  acc0 += __shfl_xor(acc0, 32);
  acc1 += __shfl_xor(acc1, 32);
  if (lane < 32) {
    const int nbase = nb * 256 + wave * 64;
    psum[(size_t)ss * NROWS + nbase + lane] = acc0;
    psum[(size_t)ss * NROWS + nbase + 32 + lane] = acc1;
  }
}

// Per-row CE + weighted partial sums (deterministic two-stage reduction).
__global__ void finish_kernel(const float* __restrict__ psum,
                              const float* __restrict__ pl,
                              const int* __restrict__ tgt,
                              const float* __restrict__ wts,
                              float* __restrict__ fin) {
  const int n = blockIdx.x * 256 + threadIdx.x;
  float tot = 0.f;
#pragma unroll
  for (int s = 0; s < SSPLIT; ++s) tot += psum[(size_t)s * NROWS + n];
  const float p = pl[n];
  tot += EXP2(p * LOG2EF);             // + exp(pos_logit), unshifted
  const float ce = logf(tot) - p;      // logZ - pos_logit
  const float w = wts[n] * (tgt[n] != -100 ? 1.f : 0.f);
  float a = wave_sum(ce * w);
  float b = wave_sum(w);
  __shared__ float sa[4], sb[4];
  const int wave = threadIdx.x >> 6, lane = threadIdx.x & 63;
  if (lane == 0) { sa[wave] = a; sb[wave] = b; }
  __syncthreads();
  if (threadIdx.x == 0) {
    fin[blockIdx.x * 2] = sa[0] + sa[1] + sa[2] + sa[3];
    fin[blockIdx.x * 2 + 1] = sb[0] + sb[1] + sb[2] + sb[3];
  }
}

__global__ void final_kernel(const float* __restrict__ fin, float* __restrict__ out) {
  const int l = threadIdx.x;
  float a = wave_sum(fin[l * 2]);
  float b = wave_sum(fin[l * 2 + 1]);
  if (l == 0) out[0] = a / fmaxf(b, 1e-12f);
}

extern "C" void kernel_launch(void* const* d_in, const int* in_sizes, int n_in,
                              void* d_out, int out_size, void* d_ws, size_t ws_size,
                              hipStream_t stream) {
  const float* x    = (const float*)d_in[0];
  const int*   tgt  = (const int*)d_in[1];
  const int*   nid  = (const int*)d_in[2];
  const float* wts  = (const float*)d_in[3];
  const float* proj = (const float*)d_in[4];
  float* out = (float*)d_out;
  char* ws = (char*)d_ws;
  __bf16* xf = (__bf16*)(ws + XF_OFF);
  __bf16* ef = (__bf16*)(ws + EF_OFF);
  float* pl   = (float*)(ws + PL_OFF);
  float* psum = (float*)(ws + PS_OFF);
  float* fin  = (float*)(ws + FP_OFF);

  hipLaunchKernelGGL(prep_kernel, dim3(4096 + 2048), dim3(256), 0, stream,
                     x, tgt, nid, proj, xf, ef, pl);
  hipLaunchKernelGGL(flash_kernel, dim3(64 * SSPLIT), dim3(256), 0, stream,
                     xf, ef, psum);
  hipLaunchKernelGGL(finish_kernel, dim3(NROWS / 256), dim3(256), 0, stream,
                     psum, pl, tgt, wts, fin);
  hipLaunchKernelGGL(final_kernel, dim3(1), dim3(64), 0, stream, fin, out);
}